// Round 5
// baseline (637.780 us; speedup 1.0000x reference)
//
#include <hip/hip_runtime.h>
#include <hip/hip_bf16.h>
#include <stdint.h>

#define KDIM 1024
#define NPAD 416                    // 26 col-tiles of 16 (405 real cols + 11 pad)
#define NCOLS 405
#define SCORE_COLS 81
#define BBOX_COLS 324
#define NROWS 65536
#define FDIM 300
#define SLAB (NPAD * 32)            // bf16 elems per 32-k block = 13312

// Blocked Wt layout: element (row, k) -> (k>>5)*SLAB + row*32 + (k&31)
// i.e. [kt][416 cols][32 k]; a wave's 16-col fragment is a coalesced 1 KB chunk.

typedef short v8s __attribute__((ext_vector_type(8)));
typedef float v4f __attribute__((ext_vector_type(4)));

__device__ __forceinline__ uint16_t f2bf(float f) {
    union { float f; uint32_t u; } c; c.f = f;
    uint32_t r = c.u + 0x7FFFu + ((c.u >> 16) & 1u);
    return (uint16_t)(r >> 16);
}

__device__ __forceinline__ size_t wt_off(int row, int k) {
    return (size_t)(k >> 5) * SLAB + (size_t)row * 32 + (k & 31);
}

// ---- prep: W_total rows 0 (cls), 81..404 (bbox), 405..415 (zero pad) + biases
__global__ void fill_w(const float* __restrict__ Wcls, const float* __restrict__ bcls,
                       const float* __restrict__ Wbbox, const float* __restrict__ bbbox,
                       uint16_t* __restrict__ Wt, float* __restrict__ bt) {
    int idx = blockIdx.x * 256 + threadIdx.x;        // NPAD*1024 total
    int row = idx >> 10, k = idx & 1023;
    if (!(row >= 1 && row < 81)) {                   // rows 1..80 done by fill_w_sem
        float v;
        if (row == 0) v = Wcls[k];
        else if (row < 81 + BBOX_COLS) v = Wbbox[(size_t)(row - 81) * KDIM + k];
        else v = 0.f;
        Wt[wt_off(row, k)] = f2bf(v);
    }
    if (k == 0 && !(row >= 1 && row < 81)) {
        float b;
        if (row == 0) b = bcls[0];
        else if (row < 81 + BBOX_COLS) b = bbbox[row - 81];
        else b = 0.f;
        bt[row] = b;
    }
}

// ---- prep: W_total rows 1..80 = (8/||sem_row||) * (sem_row @ W_sem)
__global__ void fill_w_sem(const float* __restrict__ Wsem, const float* __restrict__ bsem,
                           const float* __restrict__ semm,
                           uint16_t* __restrict__ Wt, float* __restrict__ bt) {
    const int n = blockIdx.x;          // 0..79
    const int kq = blockIdx.y;         // 0..3
    const int tid = threadIdx.x;       // 256
    __shared__ float s_row[FDIM];
    __shared__ float red[256];
    __shared__ float s_scale, s_bdot;

    const float* sr = semm + (size_t)n * FDIM;
    float p = 0.f, pb = 0.f;
    for (int f = tid; f < FDIM; f += 256) {
        float v = sr[f];
        s_row[f] = v;
        p += v * v;
        pb += v * bsem[f];
    }
    red[tid] = p; __syncthreads();
    for (int s = 128; s > 0; s >>= 1) { if (tid < s) red[tid] += red[tid + s]; __syncthreads(); }
    float norm2 = red[0]; __syncthreads();
    red[tid] = pb; __syncthreads();
    for (int s = 128; s > 0; s >>= 1) { if (tid < s) red[tid] += red[tid + s]; __syncthreads(); }
    if (tid == 0) { s_scale = 8.0f / sqrtf(norm2); s_bdot = red[0]; }
    __syncthreads();
    const float scale = s_scale;
    if (kq == 0 && tid == 0) bt[1 + n] = scale * s_bdot;

    const int k = kq * 256 + tid;      // exactly one k per thread
    float acc = 0.f;
    #pragma unroll 8
    for (int f = 0; f < FDIM; ++f) acc += s_row[f] * Wsem[(size_t)f * KDIM + k];
    Wt[wt_off(1 + n, k)] = f2bf(scale * acc);
}

// ---- fused GEMM: one block = 64 rows x ALL 416 cols (x read exactly once)
// ZERO synchronization in the K loop: no LDS staging, no barriers, no asm waits.
// A fragments are loaded DIRECTLY per-lane from x (lane (quad,l16) reads
// x[row=mi*16+l16][kt*32+quad*8..+8] as two float4 -- the 64 lane-segments
// exactly tile 16 x 128B cache lines) and packed fp32->bf16 in-register.
// B fragments direct L2->VGPR, reloaded right after last use (1-iter cover).
// Latency hiding comes from 4 unsynchronized waves/SIMD, not lockstep pipelining.
// Column tiles: t = wave + 8*ni; waves 0-1 own 4 tiles, waves 2-7 own 3 (26 total).
#define EPS_STRIDE 409
#define SMEM_BYTES (32 * EPS_STRIDE * 4)  // 52352 (epilogue staging only)

__device__ __forceinline__ v8s pack8(float4 f0, float4 f1) {
    __hip_bfloat162 p0 = __float22bfloat162_rn(make_float2(f0.x, f0.y));
    __hip_bfloat162 p1 = __float22bfloat162_rn(make_float2(f0.z, f0.w));
    __hip_bfloat162 p2 = __float22bfloat162_rn(make_float2(f1.x, f1.y));
    __hip_bfloat162 p3 = __float22bfloat162_rn(make_float2(f1.z, f1.w));
    union { v8s v; uint32_t u[4]; } r;
    r.u[0] = *(uint32_t*)&p0; r.u[1] = *(uint32_t*)&p1;
    r.u[2] = *(uint32_t*)&p2; r.u[3] = *(uint32_t*)&p3;
    return r.v;
}

__global__ __launch_bounds__(512, 4) void gemm_fused(
        const float* __restrict__ x, const uint16_t* __restrict__ Wt,
        const float* __restrict__ bt, float* __restrict__ out) {
    const int tid = threadIdx.x;
    const int wave = tid >> 6, lane = tid & 63;
    const int quad = lane >> 4, l16 = lane & 15;
    const int mtile = blockIdx.x;
    const bool four = (wave < 2);        // waves 0,1: 4 tiles; waves 2-7: 3 tiles

    __shared__ __align__(16) char smem[SMEM_BYTES];

    v4f acc[4][4];
    #pragma unroll
    for (int mi = 0; mi < 4; ++mi)
        #pragma unroll
        for (int ni = 0; ni < 4; ++ni)
            acc[mi][ni] = v4f{0.f, 0.f, 0.f, 0.f};

    // A: per-lane direct address. row = mtile*64 + mi*16 + l16, k0 = kt*32 + quad*8
    const float* ap = x + ((size_t)(mtile * 64 + l16)) * KDIM + quad * 8;

    // B fragment base pointers; tile t = wave + 8*ni (clamped slot unused)
    const uint16_t* bfrag[4];
    #pragma unroll
    for (int ni = 0; ni < 4; ++ni) {
        int t = wave + 8 * ni; if (t > 25) t = 25;
        bfrag[ni] = Wt + (size_t)(t * 16 + l16) * 32 + quad * 8;
    }

    v8s bcur[4];
    bcur[0] = *(const v8s*)bfrag[0];
    bcur[1] = *(const v8s*)bfrag[1];
    bcur[2] = *(const v8s*)bfrag[2];
    bcur[3] = four ? *(const v8s*)bfrag[3] : v8s{0, 0, 0, 0, 0, 0, 0, 0};

    for (int kt = 0; kt < 32; ++kt) {
        v8s a[4];
        #pragma unroll
        for (int mi = 0; mi < 4; ++mi) {
            const float* p = ap + (size_t)mi * 16 * KDIM + kt * 32;
            float4 f0 = *(const float4*)p;
            float4 f1 = *(const float4*)(p + 4);
            a[mi] = pack8(f0, f1);
        }
        const size_t nxt = (size_t)((kt + 1) & 31) * SLAB;   // kt=31 wraps: harmless L2 hit
        #pragma unroll
        for (int ni = 0; ni < 3; ++ni) {
            acc[0][ni] = __builtin_amdgcn_mfma_f32_16x16x32_bf16(a[0], bcur[ni], acc[0][ni], 0, 0, 0);
            acc[1][ni] = __builtin_amdgcn_mfma_f32_16x16x32_bf16(a[1], bcur[ni], acc[1][ni], 0, 0, 0);
            acc[2][ni] = __builtin_amdgcn_mfma_f32_16x16x32_bf16(a[2], bcur[ni], acc[2][ni], 0, 0, 0);
            acc[3][ni] = __builtin_amdgcn_mfma_f32_16x16x32_bf16(a[3], bcur[ni], acc[3][ni], 0, 0, 0);
            bcur[ni] = *(const v8s*)(bfrag[ni] + nxt);       // reload right after last use
        }
        if (four) {
            acc[0][3] = __builtin_amdgcn_mfma_f32_16x16x32_bf16(a[0], bcur[3], acc[0][3], 0, 0, 0);
            acc[1][3] = __builtin_amdgcn_mfma_f32_16x16x32_bf16(a[1], bcur[3], acc[1][3], 0, 0, 0);
            acc[2][3] = __builtin_amdgcn_mfma_f32_16x16x32_bf16(a[2], bcur[3], acc[2][3], 0, 0, 0);
            acc[3][3] = __builtin_amdgcn_mfma_f32_16x16x32_bf16(a[3], bcur[3], acc[3][3], 0, 0, 0);
            bcur[3] = *(const v8s*)(bfrag[3] + nxt);
        }
    }

    // ---- epilogue: stage through LDS (full-line coalesced, nontemporal stores)
    const int rowbase = mtile * 64;
    float* eps = (float*)smem;
    float* outb = out + (size_t)NROWS * SCORE_COLS;
    const int NT = four ? 4 : 3;
    float bias[4];
    #pragma unroll
    for (int ni = 0; ni < 4; ++ni) {
        const int col = (wave + 8 * ni) * 16 + l16;   // <= 415 < NPAD for used slots
        bias[ni] = (ni < NT) ? bt[col <= 415 ? col : 0] : 0.f;
    }
    #pragma unroll
    for (int h = 0; h < 2; ++h) {
        __syncthreads();                       // all 512 threads reach this uniformly
        #pragma unroll
        for (int mi2 = 0; mi2 < 2; ++mi2) {
            const int mi = h * 2 + mi2;
            #pragma unroll
            for (int ni = 0; ni < 4; ++ni) {
                const int col = (wave + 8 * ni) * 16 + l16;
                if (ni < NT && col < NCOLS) {
                    #pragma unroll
                    for (int r = 0; r < 4; ++r)
                        eps[(mi2 * 16 + quad * 4 + r) * EPS_STRIDE + col] = acc[mi][ni][r] + bias[ni];
                }
            }
        }
        __syncthreads();
        const int row0 = rowbase + h * 32;
        for (int idx = tid; idx < 32 * SCORE_COLS; idx += 512) {
            int r = idx / SCORE_COLS, c = idx - r * SCORE_COLS;
            __builtin_nontemporal_store(eps[r * EPS_STRIDE + c],
                                        &out[(size_t)(row0 + r) * SCORE_COLS + c]);
        }
        for (int idx = tid; idx < 32 * BBOX_COLS; idx += 512) {
            int r = idx / BBOX_COLS, c = idx - r * BBOX_COLS;
            __builtin_nontemporal_store(eps[r * EPS_STRIDE + SCORE_COLS + c],
                                        &outb[(size_t)(row0 + r) * BBOX_COLS + c]);
        }
    }
}

extern "C" void kernel_launch(void* const* d_in, const int* in_sizes, int n_in,
                              void* d_out, int out_size, void* d_ws, size_t ws_size,
                              hipStream_t stream) {
    const float* x     = (const float*)d_in[0];
    const float* Wcls  = (const float*)d_in[1];
    const float* bcls  = (const float*)d_in[2];
    const float* Wsem  = (const float*)d_in[3];
    const float* bsem  = (const float*)d_in[4];
    const float* Wbbox = (const float*)d_in[5];
    const float* bbbox = (const float*)d_in[6];
    const float* semm  = (const float*)d_in[7];
    float* out = (float*)d_out;

    uint16_t* Wt = (uint16_t*)d_ws;                                  // 416*1024*2 = 832 KB (blocked)
    float*    bt = (float*)((char*)d_ws + (size_t)NPAD * KDIM * 2);  // 1.7 KB

    fill_w<<<dim3((NPAD * KDIM) / 256), dim3(256), 0, stream>>>(Wcls, bcls, Wbbox, bbbox, Wt, bt);
    fill_w_sem<<<dim3(80, 4), dim3(256), 0, stream>>>(Wsem, bsem, semm, Wt, bt);
    gemm_fused<<<dim3(NROWS / 64), dim3(512), 0, stream>>>(x, Wt, bt, out);
}

// Round 6
// 539.750 us; speedup vs baseline: 1.1816x; 1.1816x over previous
//
#include <hip/hip_runtime.h>
#include <hip/hip_bf16.h>
#include <stdint.h>

#define KDIM 1024
#define NPAD 416                    // 26 col-tiles of 16 (405 real cols + 11 pad)
#define NCOLS 405
#define SCORE_COLS 81
#define BBOX_COLS 324
#define NROWS 65536
#define FDIM 300
#define SLAB (NPAD * 32)            // bf16 elems per 32-k block = 13312

// Blocked Wt layout: element (row, k) -> (k>>5)*SLAB + row*32 + (k&31)
// i.e. [kt][416 cols][32 k]; a wave's 16-col fragment is a coalesced 1 KB chunk.

typedef short v8s __attribute__((ext_vector_type(8)));
typedef float v4f __attribute__((ext_vector_type(4)));

__device__ __forceinline__ uint16_t f2bf(float f) {
    union { float f; uint32_t u; } c; c.f = f;
    uint32_t r = c.u + 0x7FFFu + ((c.u >> 16) & 1u);
    return (uint16_t)(r >> 16);
}

__device__ __forceinline__ size_t wt_off(int row, int k) {
    return (size_t)(k >> 5) * SLAB + (size_t)row * 32 + (k & 31);
}

// ---- prep: W_total rows 0 (cls), 81..404 (bbox), 405..415 (zero pad) + biases
__global__ void fill_w(const float* __restrict__ Wcls, const float* __restrict__ bcls,
                       const float* __restrict__ Wbbox, const float* __restrict__ bbbox,
                       uint16_t* __restrict__ Wt, float* __restrict__ bt) {
    int idx = blockIdx.x * 256 + threadIdx.x;        // NPAD*1024 total
    int row = idx >> 10, k = idx & 1023;
    if (!(row >= 1 && row < 81)) {                   // rows 1..80 done by fill_w_sem
        float v;
        if (row == 0) v = Wcls[k];
        else if (row < 81 + BBOX_COLS) v = Wbbox[(size_t)(row - 81) * KDIM + k];
        else v = 0.f;
        Wt[wt_off(row, k)] = f2bf(v);
    }
    if (k == 0 && !(row >= 1 && row < 81)) {
        float b;
        if (row == 0) b = bcls[0];
        else if (row < 81 + BBOX_COLS) b = bbbox[row - 81];
        else b = 0.f;
        bt[row] = b;
    }
}

// ---- prep: W_total rows 1..80 = (8/||sem_row||) * (sem_row @ W_sem)
__global__ void fill_w_sem(const float* __restrict__ Wsem, const float* __restrict__ bsem,
                           const float* __restrict__ semm,
                           uint16_t* __restrict__ Wt, float* __restrict__ bt) {
    const int n = blockIdx.x;          // 0..79
    const int kq = blockIdx.y;         // 0..3
    const int tid = threadIdx.x;       // 256
    __shared__ float s_row[FDIM];
    __shared__ float red[256];
    __shared__ float s_scale, s_bdot;

    const float* sr = semm + (size_t)n * FDIM;
    float p = 0.f, pb = 0.f;
    for (int f = tid; f < FDIM; f += 256) {
        float v = sr[f];
        s_row[f] = v;
        p += v * v;
        pb += v * bsem[f];
    }
    red[tid] = p; __syncthreads();
    for (int s = 128; s > 0; s >>= 1) { if (tid < s) red[tid] += red[tid + s]; __syncthreads(); }
    float norm2 = red[0]; __syncthreads();
    red[tid] = pb; __syncthreads();
    for (int s = 128; s > 0; s >>= 1) { if (tid < s) red[tid] += red[tid + s]; __syncthreads(); }
    if (tid == 0) { s_scale = 8.0f / sqrtf(norm2); s_bdot = red[0]; }
    __syncthreads();
    const float scale = s_scale;
    if (kq == 0 && tid == 0) bt[1 + n] = scale * s_bdot;

    const int k = kq * 256 + tid;      // exactly one k per thread
    float acc = 0.f;
    #pragma unroll 8
    for (int f = 0; f < FDIM; ++f) acc += s_row[f] * Wsem[(size_t)f * KDIM + k];
    Wt[wt_off(1 + n, k)] = f2bf(scale * acc);
}

// ---- fused GEMM: 4-wave blocks, BM=32 rows x ALL 26 col-tiles.
// Rationale (R6): per-step latency (~3K cy) is structural; the lever is the
// number of INDEPENDENT barrier domains per CU. acc=56 + ~64 working regs
// keeps unified <=128 -> 4 waves/SIMD -> FOUR independent 4-wave blocks/CU
// (vs two 8-wave blocks before), and each barrier syncs only 4 waves.
// x stays read-once (LDS-staged per block); wave w owns tiles w+4*ni,
// NT={7,7,6,6} -- zero dummy MFMA/loads. K-loop keeps the R4-proven order:
// A issued LAST (FIFO: B-waits never drain the HBM A load; stcvt's A has
// 2 iters of cover). Epilogue: direct dword stores, L2 merges segments.
#define BM 32
#define A_STRIDE 36                     // bf16 elems per A row in LDS (bank-friendly)
#define A_BUF_ELEMS (BM * A_STRIDE)     // 1152

__device__ __forceinline__ void stcvt(uint16_t* p, float4 av) {
    __hip_bfloat162 lo = __float22bfloat162_rn(make_float2(av.x, av.y));
    __hip_bfloat162 hi = __float22bfloat162_rn(make_float2(av.z, av.w));
    uint2 v; v.x = *(uint32_t*)&lo; v.y = *(uint32_t*)&hi;
    *(uint2*)p = v;
}

__global__ __launch_bounds__(256, 4) void gemm_fused(
        const float* __restrict__ x, const uint16_t* __restrict__ Wt,
        const float* __restrict__ bt, float* __restrict__ out) {
    const int tid = threadIdx.x;
    const int wave = tid >> 6, lane = tid & 63;
    const int quad = lane >> 4, l16 = lane & 15;
    const int mtile = blockIdx.x;                 // 2048 blocks of 32 rows
    const int NT = (wave < 2) ? 7 : 6;            // tiles: t = wave + 4*ni (26 exact)

    __shared__ __align__(16) uint16_t As[2][A_BUF_ELEMS];   // 4.6 KB total

    const float* xb = x + (size_t)mtile * BM * KDIM;

    v4f acc[2][7];
    #pragma unroll
    for (int mi = 0; mi < 2; ++mi)
        #pragma unroll
        for (int ni = 0; ni < 7; ++ni)
            acc[mi][ni] = v4f{0.f, 0.f, 0.f, 0.f};

    const int am = tid >> 3, akc = tid & 7;        // A: row (0..31), 4-float chunk (0..7)
    const float* aptr = xb + (size_t)am * KDIM + akc * 4;          // +32 floats per kt

    const uint16_t* bfrag[7];
    #pragma unroll
    for (int ni = 0; ni < 7; ++ni) {
        int t = wave + 4 * ni; if (t > 25) t = 25;   // slot ni>=NT never loaded
        bfrag[ni] = Wt + (size_t)(t * 16 + l16) * 32 + quad * 8;
    }

    v8s bcur[7];
    float4 av_n, av_nn;

    // ---- prologue: A(0) staged; A(1), A(2) and B(0) in flight
    {
        float4 av0 = *(const float4*)aptr;
        av_n  = *(const float4*)(aptr + 32);
        av_nn = *(const float4*)(aptr + 64);
        #pragma unroll
        for (int ni = 0; ni < 7; ++ni)
            if (ni < NT) bcur[ni] = *(const v8s*)bfrag[ni];
        stcvt(&As[0][am * A_STRIDE + akc * 4], av0);
        asm volatile("s_waitcnt lgkmcnt(0)" ::: "memory");
        __builtin_amdgcn_s_barrier();
        asm volatile("" ::: "memory");
    }

    // ---- main loop: kt = 0..28, 1 raw barrier/iter, 4-wave domain.
    // FIFO queue at iter kt (oldest->newest): [B(kt)xNT, A(kt+2)];
    // stcvt consumes A(kt+1) (2-iter cover, no stall); MFMAs wait only B(kt).
    int rb = 0;
    for (int kt = 0; kt < 29; ++kt) {
        const uint16_t* Ar = &As[rb][0];
        v8s a0 = *(const v8s*)(Ar + (0 * 16 + l16) * A_STRIDE + quad * 8);
        v8s a1 = *(const v8s*)(Ar + (1 * 16 + l16) * A_STRIDE + quad * 8);
        stcvt(&As[rb ^ 1][am * A_STRIDE + akc * 4], av_n);   // A(kt+1)
        av_n = av_nn;
        const size_t nxt = (size_t)(kt + 1) * SLAB;
        #pragma unroll
        for (int ni = 0; ni < 7; ++ni) {
            if (ni < NT) {
                acc[0][ni] = __builtin_amdgcn_mfma_f32_16x16x32_bf16(a0, bcur[ni], acc[0][ni], 0, 0, 0);
                acc[1][ni] = __builtin_amdgcn_mfma_f32_16x16x32_bf16(a1, bcur[ni], acc[1][ni], 0, 0, 0);
                bcur[ni] = *(const v8s*)(bfrag[ni] + nxt);   // B(kt+1)
            }
        }
        // pin the A prefetch AFTER the B loads in VMEM issue order
        __builtin_amdgcn_sched_barrier(0);
        av_nn = *(const float4*)(aptr + (size_t)(kt + 3) * 32);      // A(kt+3), newest
        asm volatile("s_waitcnt lgkmcnt(0)" ::: "memory");
        __builtin_amdgcn_s_barrier();
        asm volatile("" ::: "memory");
        rb ^= 1;
    }

    // ---- kt = 29 (peeled: no A-global prefetch)
    {
        const uint16_t* Ar = &As[rb][0];
        v8s a0 = *(const v8s*)(Ar + (0 * 16 + l16) * A_STRIDE + quad * 8);
        v8s a1 = *(const v8s*)(Ar + (1 * 16 + l16) * A_STRIDE + quad * 8);
        stcvt(&As[rb ^ 1][am * A_STRIDE + akc * 4], av_n);   // A(30)
        av_n = av_nn;
        const size_t nxt = (size_t)30 * SLAB;
        #pragma unroll
        for (int ni = 0; ni < 7; ++ni) {
            if (ni < NT) {
                acc[0][ni] = __builtin_amdgcn_mfma_f32_16x16x32_bf16(a0, bcur[ni], acc[0][ni], 0, 0, 0);
                acc[1][ni] = __builtin_amdgcn_mfma_f32_16x16x32_bf16(a1, bcur[ni], acc[1][ni], 0, 0, 0);
                bcur[ni] = *(const v8s*)(bfrag[ni] + nxt);   // B(30)
            }
        }
        asm volatile("s_waitcnt lgkmcnt(0)" ::: "memory");
        __builtin_amdgcn_s_barrier();
        asm volatile("" ::: "memory");
        rb ^= 1;
    }

    // ---- kt = 30 (peeled)
    {
        const uint16_t* Ar = &As[rb][0];
        v8s a0 = *(const v8s*)(Ar + (0 * 16 + l16) * A_STRIDE + quad * 8);
        v8s a1 = *(const v8s*)(Ar + (1 * 16 + l16) * A_STRIDE + quad * 8);
        stcvt(&As[rb ^ 1][am * A_STRIDE + akc * 4], av_n);   // A(31)
        const size_t nxt = (size_t)31 * SLAB;
        #pragma unroll
        for (int ni = 0; ni < 7; ++ni) {
            if (ni < NT) {
                acc[0][ni] = __builtin_amdgcn_mfma_f32_16x16x32_bf16(a0, bcur[ni], acc[0][ni], 0, 0, 0);
                acc[1][ni] = __builtin_amdgcn_mfma_f32_16x16x32_bf16(a1, bcur[ni], acc[1][ni], 0, 0, 0);
                bcur[ni] = *(const v8s*)(bfrag[ni] + nxt);   // B(31)
            }
        }
        asm volatile("s_waitcnt lgkmcnt(0)" ::: "memory");
        __builtin_amdgcn_s_barrier();
        asm volatile("" ::: "memory");
        rb ^= 1;
    }

    // ---- kt = 31 (peeled: compute only)
    {
        const uint16_t* Ar = &As[rb][0];
        v8s a0 = *(const v8s*)(Ar + (0 * 16 + l16) * A_STRIDE + quad * 8);
        v8s a1 = *(const v8s*)(Ar + (1 * 16 + l16) * A_STRIDE + quad * 8);
        #pragma unroll
        for (int ni = 0; ni < 7; ++ni) {
            if (ni < NT) {
                acc[0][ni] = __builtin_amdgcn_mfma_f32_16x16x32_bf16(a0, bcur[ni], acc[0][ni], 0, 0, 0);
                acc[1][ni] = __builtin_amdgcn_mfma_f32_16x16x32_bf16(a1, bcur[ni], acc[1][ni], 0, 0, 0);
            }
        }
    }

    // ---- epilogue: direct stores (64B segments; L2 write-merge), no LDS, no sync
    const int rowbase = mtile * BM;
    float* outb = out + (size_t)NROWS * SCORE_COLS;
    #pragma unroll
    for (int ni = 0; ni < 7; ++ni) {
        if (ni < NT) {
            const int col = (wave + 4 * ni) * 16 + l16;
            if (col < NCOLS) {
                const float bb = bt[col];
                float* base; int ldc, cc;
                if (col < SCORE_COLS) { base = out;  ldc = SCORE_COLS; cc = col; }
                else                  { base = outb; ldc = BBOX_COLS;  cc = col - SCORE_COLS; }
                #pragma unroll
                for (int mi = 0; mi < 2; ++mi)
                    #pragma unroll
                    for (int r = 0; r < 4; ++r) {
                        const int row = rowbase + mi * 16 + quad * 4 + r;
                        base[(size_t)row * ldc + cc] = acc[mi][ni][r] + bb;
                    }
            }
        }
    }
}

extern "C" void kernel_launch(void* const* d_in, const int* in_sizes, int n_in,
                              void* d_out, int out_size, void* d_ws, size_t ws_size,
                              hipStream_t stream) {
    const float* x     = (const float*)d_in[0];
    const float* Wcls  = (const float*)d_in[1];
    const float* bcls  = (const float*)d_in[2];
    const float* Wsem  = (const float*)d_in[3];
    const float* bsem  = (const float*)d_in[4];
    const float* Wbbox = (const float*)d_in[5];
    const float* bbbox = (const float*)d_in[6];
    const float* semm  = (const float*)d_in[7];
    float* out = (float*)d_out;

    uint16_t* Wt = (uint16_t*)d_ws;                                  // 416*1024*2 = 832 KB (blocked)
    float*    bt = (float*)((char*)d_ws + (size_t)NPAD * KDIM * 2);  // 1.7 KB

    fill_w<<<dim3((NPAD * KDIM) / 256), dim3(256), 0, stream>>>(Wcls, bcls, Wbbox, bbbox, Wt, bt);
    fill_w_sem<<<dim3(80, 4), dim3(256), 0, stream>>>(Wsem, bsem, semm, Wt, bt);
    gemm_fused<<<dim3(NROWS / BM), dim3(256), 0, stream>>>(x, Wt, bt, out);
}